// Round 18
// baseline (206.225 us; speedup 1.0000x reference)
//
#include <hip/hip_runtime.h>
#include <hip/hip_fp16.h>
#include <hip/hip_fp8.h>
#include <math.h>

#define NN 100000
#define NE 1600000
#define D 64
#define BSH 8                         // bin = dst >> 8  (256 nodes/bin)
#define NBIN 391                      // ceil(100000/256)
#define EB 4096                       // edges per binning block
#define NBB ((NE + EB - 1) / EB)      // 391

typedef _Float16 f16x8 __attribute__((ext_vector_type(8)));
typedef float f32x4 __attribute__((ext_vector_type(4)));
typedef int   i32x4 __attribute__((ext_vector_type(4)));
typedef float fl32x4 __attribute__((ext_vector_type(4)));

__device__ __forceinline__ int2 ldnt2(const int2* p) {
    unsigned long long r = __builtin_nontemporal_load((const unsigned long long*)p);
    int2 o;
    o.x = (int)(unsigned)(r & 0xffffffffu);
    o.y = (int)(unsigned)(r >> 32);
    return o;
}

// ---- fp8 OCP e4m3 encode/decode (gfx950 HW cvt; class fallback) ----
__device__ __forceinline__ unsigned char fp8enc(float x) {
#if defined(__has_builtin) && __has_builtin(__builtin_amdgcn_cvt_pk_fp8_f32)
    int v = __builtin_amdgcn_cvt_pk_fp8_f32(x, x, 0, false);
    return (unsigned char)(v & 0xff);
#else
    __hip_fp8_e4m3 q(x);
    return (unsigned char)q.__x;
#endif
}
__device__ __forceinline__ float fp8dec(unsigned b) {
#if defined(__has_builtin) && __has_builtin(__builtin_amdgcn_cvt_f32_fp8)
    return __builtin_amdgcn_cvt_f32_fp8((int)b, 0);
#else
    __hip_fp8_e4m3 q;
    q.__x = (unsigned char)b;
    return (float)q;
#endif
}

// ---------------- pass A: per-block bin histogram -> transposed counts[bin][blk] ----
__global__ void k_binhist(const int* __restrict__ dst, int* __restrict__ counts, int E) {
    __shared__ int h[NBIN];
    for (int i = threadIdx.x; i < NBIN; i += blockDim.x) h[i] = 0;
    __syncthreads();
    int e0 = blockIdx.x * EB;
    int e1 = min(e0 + EB, E);
    for (int e = e0 + (int)threadIdx.x * 4; e < e1; e += blockDim.x * 4) {
        i32x4 d4 = __builtin_nontemporal_load((const i32x4*)(dst + e));
        atomicAdd(&h[d4.x >> BSH], 1);
        atomicAdd(&h[d4.y >> BSH], 1);
        atomicAdd(&h[d4.z >> BSH], 1);
        atomicAdd(&h[d4.w >> BSH], 1);
    }
    __syncthreads();
    for (int i = threadIdx.x; i < NBIN; i += blockDim.x)
        counts[(size_t)i * NBB + blockIdx.x] = h[i];   // scattered 4B, L2-absorbed
}

// ---------------- parallel scan 1: block b scans its bin's NBB block-counts ----------
__global__ void k_binscan(int* __restrict__ counts, int* __restrict__ binTot) {
    __shared__ int sm[512];
    int b = blockIdx.x, t = threadIdx.x;
    int v0 = (t < NBB)       ? counts[(size_t)b * NBB + t] : 0;
    int v1 = (t + 256 < NBB) ? counts[(size_t)b * NBB + t + 256] : 0;
    sm[t] = v0; sm[t + 256] = v1;
    __syncthreads();
    for (int off = 1; off < 512; off <<= 1) {   // Hillis-Steele inclusive over 512
        int a0 = (t >= off) ? sm[t - off] : 0;
        int a1 = (t + 256 >= off) ? sm[t + 256 - off] : 0;
        __syncthreads();
        sm[t] += a0; sm[t + 256] += a1;
        __syncthreads();
    }
    if (t < NBB)       counts[(size_t)b * NBB + t] = sm[t] - v0;             // exclusive
    if (t + 256 < NBB) counts[(size_t)b * NBB + t + 256] = sm[t + 256] - v1;
    if (t == 0) binTot[b] = sm[511];
}

// ---------------- parallel scan 2: one block scans the NBIN bin totals ----------
__global__ void k_binscan2(const int* __restrict__ binTot, int* __restrict__ binStart) {
    __shared__ int sm[512];
    int t = threadIdx.x;
    int v = (t < NBIN) ? binTot[t] : 0;
    sm[t] = v;
    __syncthreads();
    for (int off = 1; off < 512; off <<= 1) {
        int add = (t >= off) ? sm[t - off] : 0;
        __syncthreads();
        sm[t] += add;
        __syncthreads();
    }
    if (t < NBIN) binStart[t] = sm[t] - v;       // exclusive bin base
    if (t == NBIN - 1) binStart[NBIN] = sm[t];   // == E
}

// ---------------- pass B: scatter edges into bin-contiguous order ----------------
__global__ void k_binscatter(const int* __restrict__ src, const int* __restrict__ dst,
                             const float* __restrict__ w, const int* __restrict__ counts,
                             const int* __restrict__ binStart, int2* __restrict__ binned,
                             int E) {
    __shared__ int cur[NBIN];
    for (int i = threadIdx.x; i < NBIN; i += blockDim.x)
        cur[i] = binStart[i] + counts[(size_t)i * NBB + blockIdx.x];  // L2-hot
    __syncthreads();
    int e0 = blockIdx.x * EB;
    int e1 = min(e0 + EB, E);
    for (int e = e0 + (int)threadIdx.x * 4; e < e1; e += blockDim.x * 4) {
        i32x4  d4 = __builtin_nontemporal_load((const i32x4*)(dst + e));
        i32x4  s4 = __builtin_nontemporal_load((const i32x4*)(src + e));
        fl32x4 w4 = __builtin_nontemporal_load((const fl32x4*)(w + e));
        int pos;
        pos = atomicAdd(&cur[d4.x >> BSH], 1);
        binned[pos] = make_int2(((d4.x & 255) << 17) | s4.x, __float_as_int(w4.x));
        pos = atomicAdd(&cur[d4.y >> BSH], 1);
        binned[pos] = make_int2(((d4.y & 255) << 17) | s4.y, __float_as_int(w4.y));
        pos = atomicAdd(&cur[d4.z >> BSH], 1);
        binned[pos] = make_int2(((d4.z & 255) << 17) | s4.z, __float_as_int(w4.z));
        pos = atomicAdd(&cur[d4.w >> BSH], 1);
        binned[pos] = make_int2(((d4.w & 255) << 17) | s4.w, __float_as_int(w4.w));
    }
}

// ---------------- fused deg + CSR: dinv/row_ptr (pass 1) + rank/copy (pass 2) ------
// Edge record = (src, raw w bits): dinv factors are applied in gemm (src side)
// and in the agg epilogue (dst side, hoisted out of the row sum).
__global__ void k_degcsr(const int2* __restrict__ binned, const int* __restrict__ binStart,
                         float* __restrict__ dinv, int* __restrict__ row_ptr,
                         int2* __restrict__ edges, int n) {
    __shared__ int   cnt[256];
    __shared__ float ws[256];
    __shared__ int   off[256];
    __shared__ int   rp[256];
    int b = blockIdx.x, t = threadIdx.x;
    cnt[t] = 0; ws[t] = 0.0f;
    __syncthreads();
    int e0 = binStart[b], e1 = binStart[b + 1];
    for (int e = e0 + t; e < e1; e += 256) {
        int2 r = binned[e];
        int dlow = (unsigned)r.x >> 17;
        atomicAdd(&cnt[dlow], 1);
        atomicAdd(&ws[dlow], __int_as_float(r.y));
    }
    __syncthreads();
    int v = cnt[t];
    off[t] = v;
    __syncthreads();
    for (int o = 1; o < 256; o <<= 1) {
        int add = (t >= o) ? off[t - o] : 0;
        __syncthreads();
        off[t] += add;
        __syncthreads();
    }
    int node = b * 256 + t;
    rp[t] = e0 + off[t] - v;                 // exclusive row base
    if (node < n) {
        dinv[node] = rsqrtf(1.0f + ws[t]);   // self-loop weight 1
        row_ptr[node] = rp[t];
    }
    if (b == NBIN - 1 && t == 0) row_ptr[n] = binStart[NBIN];
    cnt[t] = 0;                              // reuse as rank cursor
    __syncthreads();
    for (int e = e0 + t; e < e1; e += 256) { // pass 2: bin is L2-hot, pure rank+copy
        int2 r = binned[e];
        int dlow = (unsigned)r.x >> 17;
        int rank = atomicAdd(&cnt[dlow], 1);
        edges[rp[dlow] + rank] = make_int2(r.x & 0x1FFFF, r.y);
    }
}

// ---------------- dense: T' = dinv ⊙ (X @ W) via MFMA, fp8 e4m3 output rows --------
// Wave computes 32 rows (2 tiles of 16). A/B frag: lane&15 = row/col,
// 8 contiguous k at (lane>>4)*8. C/D: col=lane&15, row=(lane>>4)*4+reg.
template <int IN_HALF>
__global__ void k_gemm(const void* __restrict__ Xv, const float* __restrict__ W,
                       const float* __restrict__ dinv, unsigned char* __restrict__ T8,
                       int n) {
    int wid = (int)((blockIdx.x * blockDim.x + threadIdx.x) >> 6);
    int lane = threadIdx.x & 63;
    int col16 = lane & 15, kg = lane >> 4;
    int r0 = wid * 32;
    if (r0 >= n) return;
    // B fragments: bf[kk][ct], elem j = W[kk*32 + kg*8 + j][ct*16 + col16]
    f16x8 bf[2][4];
#pragma unroll
    for (int kk = 0; kk < 2; kk++)
#pragma unroll
        for (int ct = 0; ct < 4; ct++) {
            f16x8 b;
#pragma unroll
            for (int j = 0; j < 8; j++)
                b[j] = (_Float16)W[(size_t)(kk * 32 + kg * 8 + j) * D + ct * 16 + col16];
            bf[kk][ct] = b;
        }
#pragma unroll
    for (int tt = 0; tt < 2; tt++) {
        int row = r0 + tt * 16 + col16;           // this lane's A row
        f16x8 a0, a1;
        if (IN_HALF) {
            const _Float16* xr = (const _Float16*)Xv + (size_t)row * D;
            a0 = *(const f16x8*)(xr + kg * 8);
            a1 = *(const f16x8*)(xr + 32 + kg * 8);
        } else {
            const float* xr = (const float*)Xv + (size_t)row * D;
#pragma unroll
            for (int j = 0; j < 8; j++) {
                a0[j] = (_Float16)xr[kg * 8 + j];
                a1[j] = (_Float16)xr[32 + kg * 8 + j];
            }
        }
        float dvr[4];
#pragma unroll
        for (int r = 0; r < 4; r++) dvr[r] = dinv[r0 + tt * 16 + kg * 4 + r];
#pragma unroll
        for (int ct = 0; ct < 4; ct++) {
            f32x4 z = {0.0f, 0.0f, 0.0f, 0.0f};
            z = __builtin_amdgcn_mfma_f32_16x16x32_f16(a0, bf[0][ct], z, 0, 0, 0);
            z = __builtin_amdgcn_mfma_f32_16x16x32_f16(a1, bf[1][ct], z, 0, 0, 0);
            unsigned char* to = T8 + (size_t)(r0 + tt * 16 + kg * 4) * D + ct * 16 + col16;
#pragma unroll
            for (int r = 0; r < 4; r++)
                to[(size_t)r * D] = fp8enc(z[r] * dvr[r]);
        }
    }
}

// ---------------- aggregation on fp8 rows: lane owns channel, 1 line per edge ------
// acc = Σ w_e·T'[s] + T'[v]; out = relu(dv·acc + b). fp32 accumulate.
// Tiers 16/8/4 + scalar tail; NT edge loads (uniform across wave).
template <int FUSE_W3>
__global__ void k_agg(const unsigned char* __restrict__ T8, const int* __restrict__ row_ptr,
                      const int2* __restrict__ edges, const float* __restrict__ dinv,
                      const float* __restrict__ bias, const float* __restrict__ W3,
                      void* __restrict__ outv, int n) {
    int wave = (int)((blockIdx.x * blockDim.x + threadIdx.x) >> 6);
    int lane = threadIdx.x & 63;
    if (wave >= n) return;
    int beg = row_ptr[wave], end = row_ptr[wave + 1];
    float a0 = 0.0f, a1 = 0.0f;
    int i = beg;
    for (; i + 16 <= end; i += 16) {
        int2 er[16];
#pragma unroll
        for (int j = 0; j < 16; j++) er[j] = ldnt2(&edges[i + j]);
        unsigned bv[16];
#pragma unroll
        for (int j = 0; j < 16; j++) bv[j] = T8[(size_t)er[j].x * D + lane];
#pragma unroll
        for (int j = 0; j < 16; j++) {
            float f = fp8dec(bv[j]);
            if (j & 1) a1 += __int_as_float(er[j].y) * f;
            else       a0 += __int_as_float(er[j].y) * f;
        }
    }
    if (i + 8 <= end) {
        int2 er[8];
#pragma unroll
        for (int j = 0; j < 8; j++) er[j] = ldnt2(&edges[i + j]);
        unsigned bv[8];
#pragma unroll
        for (int j = 0; j < 8; j++) bv[j] = T8[(size_t)er[j].x * D + lane];
#pragma unroll
        for (int j = 0; j < 8; j++) {
            float f = fp8dec(bv[j]);
            if (j & 1) a1 += __int_as_float(er[j].y) * f;
            else       a0 += __int_as_float(er[j].y) * f;
        }
        i += 8;
    }
    if (i + 4 <= end) {
        int2 er[4];
#pragma unroll
        for (int j = 0; j < 4; j++) er[j] = ldnt2(&edges[i + j]);
        unsigned bv[4];
#pragma unroll
        for (int j = 0; j < 4; j++) bv[j] = T8[(size_t)er[j].x * D + lane];
#pragma unroll
        for (int j = 0; j < 4; j++) {
            float f = fp8dec(bv[j]);
            if (j & 1) a1 += __int_as_float(er[j].y) * f;
            else       a0 += __int_as_float(er[j].y) * f;
        }
        i += 4;
    }
    for (; i < end; i++) {
        int2 e = ldnt2(&edges[i]);
        a0 += __int_as_float(e.y) * fp8dec(T8[(size_t)e.x * D + lane]);
    }
    float self = fp8dec(T8[(size_t)wave * D + lane]);   // pre-scaled by dinv[v]
    float dv = dinv[wave];
    float hval = fmaxf(dv * (a0 + a1 + self) + bias[lane], 0.0f);
    if (FUSE_W3) {
        float pp = hval * W3[lane];
#pragma unroll
        for (int off = 32; off; off >>= 1) pp += __shfl_xor(pp, off);
        if (lane == 0) ((float*)outv)[wave] = dv * pp;   // store pre-scaled t3'
    } else {
        ((__half*)outv)[(size_t)wave * D + lane] = __float2half(hval);  // fp16 h (seq.)
    }
}

// ---------------- layer 3 on pre-scaled t3': sigmoid(dv·(Σ w·t3'[s] + t3'[v]) + b3) ----
__global__ void k_agg3(const float* __restrict__ t3, const int* __restrict__ row_ptr,
                       const int2* __restrict__ edges, const float* __restrict__ dinv,
                       const float* __restrict__ b3, float* __restrict__ out, int n) {
    int v = blockIdx.x * blockDim.x + threadIdx.x;
    if (v >= n) return;
    float acc0 = t3[v];                        // self-loop, weight 1
    float acc1 = 0.0f;
    int beg = row_ptr[v], end = row_ptr[v + 1];
    int i = beg;
    for (; i + 8 <= end; i += 8) {
        int2 er[8]; float av[8];
#pragma unroll
        for (int j = 0; j < 8; j++) er[j] = ldnt2(&edges[i + j]);
#pragma unroll
        for (int j = 0; j < 8; j++) av[j] = t3[er[j].x];
#pragma unroll
        for (int j = 0; j < 8; j++) {
            if (j & 1) acc1 += __int_as_float(er[j].y) * av[j];
            else       acc0 += __int_as_float(er[j].y) * av[j];
        }
    }
    for (; i < end; i++) {
        int2 e = ldnt2(&edges[i]);
        acc0 += __int_as_float(e.y) * t3[e.x];
    }
    float z = dinv[v] * (acc0 + acc1) + b3[0];
    out[v] = 1.0f / (1.0f + expf(-z));
}

extern "C" void kernel_launch(void* const* d_in, const int* in_sizes, int n_in,
                              void* d_out, int out_size, void* d_ws, size_t ws_size,
                              hipStream_t stream) {
    const float* x  = (const float*)d_in[0];
    const int*   ei = (const int*)d_in[1];
    const float* w  = (const float*)d_in[2];
    const float* W1 = (const float*)d_in[3];
    const float* b1 = (const float*)d_in[4];
    const float* W2 = (const float*)d_in[5];
    const float* b2 = (const float*)d_in[6];
    const float* W3 = (const float*)d_in[7];
    const float* b3 = (const float*)d_in[8];
    float* out = (float*)d_out;

    const int N = NN, E = NE;
    const int* src = ei;
    const int* dst = ei + E;

    // workspace carve (256B aligned)
    char* p = (char*)d_ws;
    auto alloc = [&](size_t bytes) -> char* {
        char* r = p;
        p += (bytes + 255) & ~(size_t)255;
        return r;
    };
    float* dinv    = (float*)alloc((size_t)N * 4);
    int*   row_ptr = (int*)alloc((size_t)(N + 1) * 4);
    int*   binStart= (int*)alloc((NBIN + 1) * 4);
    int*   binTot  = (int*)alloc(NBIN * 4);
    int*   counts  = (int*)alloc((size_t)NBB * NBIN * 4);
    int2*  binned  = (int2*)alloc((size_t)E * 8);       // bin-ordered records
    int2*  edges   = (int2*)alloc((size_t)E * 8);       // compact CSR (src, raw w)
    unsigned char* bufA = (unsigned char*)alloc((size_t)N * D);      // fp8 T' rows (64B)
    __half* bufB   = (__half*)alloc((size_t)N * D * 2);              // fp16 h (sequential)
    float* t3      = (float*)alloc((size_t)N * 4);

    const int BT = 256;
    int gN = (N + BT - 1) / BT;
    int gW = (N * 64 + BT - 1) / BT;               // wave-per-node grids (4 waves/block)
    int nWaves = (N + 31) / 32;                    // gemm: wave per 32 rows
    int gG = (nWaves * 64 + BT - 1) / BT;

    // --- CSR build: zero global atomics, parallel scans ---
    k_binhist<<<NBB, BT, 0, stream>>>(dst, counts, E);
    k_binscan<<<NBIN, BT, 0, stream>>>(counts, binTot);
    k_binscan2<<<1, 512, 0, stream>>>(binTot, binStart);
    k_binscatter<<<NBB, BT, 0, stream>>>(src, dst, w, counts, binStart, binned, E);
    k_degcsr<<<NBIN, BT, 0, stream>>>(binned, binStart, dinv, row_ptr, edges, N);

    // --- layer 1 ---
    k_gemm<0><<<gG, BT, 0, stream>>>(x, W1, dinv, bufA, N);
    k_agg<0><<<gW, BT, 0, stream>>>(bufA, row_ptr, edges, dinv, b1, nullptr, bufB, N);
    // --- layer 2 (fused h2 @ W3 epilogue -> t3') ---
    k_gemm<1><<<gG, BT, 0, stream>>>(bufB, W2, dinv, bufA, N);
    k_agg<1><<<gW, BT, 0, stream>>>(bufA, row_ptr, edges, dinv, b2, W3, t3, N);
    // --- layer 3: scalar aggregation + bias + sigmoid ---
    k_agg3<<<gN, BT, 0, stream>>>(t3, row_ptr, edges, dinv, b3, out, N);
}

// Round 21
// 200.647 us; speedup vs baseline: 1.0278x; 1.0278x over previous
//
#include <hip/hip_runtime.h>
#include <hip/hip_fp16.h>
#include <math.h>

#define NN 100000
#define NE 1600000
#define D 64
#define BSH 8                         // bin = dst >> 8  (256 nodes/bin)
#define NBIN 391                      // ceil(100000/256)
#define EB 4096                       // edges per binning block
#define NBB ((NE + EB - 1) / EB)      // 391

typedef _Float16 f16x8 __attribute__((ext_vector_type(8)));
typedef float f32x4 __attribute__((ext_vector_type(4)));
typedef int   i32x4 __attribute__((ext_vector_type(4)));
typedef float fl32x4 __attribute__((ext_vector_type(4)));

__device__ __forceinline__ int2 ldnt2(const int2* p) {
    unsigned long long r = __builtin_nontemporal_load((const unsigned long long*)p);
    int2 o;
    o.x = (int)(unsigned)(r & 0xffffffffu);
    o.y = (int)(unsigned)(r >> 32);
    return o;
}

// ---------------- pass A: per-block bin histogram -> transposed counts[bin][blk] ----
__global__ void k_binhist(const int* __restrict__ dst, int* __restrict__ counts, int E) {
    __shared__ int h[NBIN];
    for (int i = threadIdx.x; i < NBIN; i += blockDim.x) h[i] = 0;
    __syncthreads();
    int e0 = blockIdx.x * EB;
    int e1 = min(e0 + EB, E);
    for (int e = e0 + (int)threadIdx.x * 4; e < e1; e += blockDim.x * 4) {
        i32x4 d4 = __builtin_nontemporal_load((const i32x4*)(dst + e));
        atomicAdd(&h[d4.x >> BSH], 1);
        atomicAdd(&h[d4.y >> BSH], 1);
        atomicAdd(&h[d4.z >> BSH], 1);
        atomicAdd(&h[d4.w >> BSH], 1);
    }
    __syncthreads();
    for (int i = threadIdx.x; i < NBIN; i += blockDim.x)
        counts[(size_t)i * NBB + blockIdx.x] = h[i];   // scattered 4B, L2-absorbed
}

// ---------------- parallel scan 1: block b scans its bin's NBB block-counts ----------
__global__ void k_binscan(int* __restrict__ counts, int* __restrict__ binTot) {
    __shared__ int sm[512];
    int b = blockIdx.x, t = threadIdx.x;
    int v0 = (t < NBB)       ? counts[(size_t)b * NBB + t] : 0;
    int v1 = (t + 256 < NBB) ? counts[(size_t)b * NBB + t + 256] : 0;
    sm[t] = v0; sm[t + 256] = v1;
    __syncthreads();
    for (int off = 1; off < 512; off <<= 1) {   // Hillis-Steele inclusive over 512
        int a0 = (t >= off) ? sm[t - off] : 0;
        int a1 = (t + 256 >= off) ? sm[t + 256 - off] : 0;
        __syncthreads();
        sm[t] += a0; sm[t + 256] += a1;
        __syncthreads();
    }
    if (t < NBB)       counts[(size_t)b * NBB + t] = sm[t] - v0;             // exclusive
    if (t + 256 < NBB) counts[(size_t)b * NBB + t + 256] = sm[t + 256] - v1;
    if (t == 0) binTot[b] = sm[511];
}

// ---------------- parallel scan 2: one block scans the NBIN bin totals ----------
__global__ void k_binscan2(const int* __restrict__ binTot, int* __restrict__ binStart) {
    __shared__ int sm[512];
    int t = threadIdx.x;
    int v = (t < NBIN) ? binTot[t] : 0;
    sm[t] = v;
    __syncthreads();
    for (int off = 1; off < 512; off <<= 1) {
        int add = (t >= off) ? sm[t - off] : 0;
        __syncthreads();
        sm[t] += add;
        __syncthreads();
    }
    if (t < NBIN) binStart[t] = sm[t] - v;       // exclusive bin base
    if (t == NBIN - 1) binStart[NBIN] = sm[t];   // == E
}

// ---------------- pass B: scatter edges into bin-contiguous order ----------------
__global__ void k_binscatter(const int* __restrict__ src, const int* __restrict__ dst,
                             const float* __restrict__ w, const int* __restrict__ counts,
                             const int* __restrict__ binStart, int2* __restrict__ binned,
                             int E) {
    __shared__ int cur[NBIN];
    for (int i = threadIdx.x; i < NBIN; i += blockDim.x)
        cur[i] = binStart[i] + counts[(size_t)i * NBB + blockIdx.x];  // L2-hot
    __syncthreads();
    int e0 = blockIdx.x * EB;
    int e1 = min(e0 + EB, E);
    for (int e = e0 + (int)threadIdx.x * 4; e < e1; e += blockDim.x * 4) {
        i32x4  d4 = __builtin_nontemporal_load((const i32x4*)(dst + e));
        i32x4  s4 = __builtin_nontemporal_load((const i32x4*)(src + e));
        fl32x4 w4 = __builtin_nontemporal_load((const fl32x4*)(w + e));
        int pos;
        pos = atomicAdd(&cur[d4.x >> BSH], 1);
        binned[pos] = make_int2(((d4.x & 255) << 17) | s4.x, __float_as_int(w4.x));
        pos = atomicAdd(&cur[d4.y >> BSH], 1);
        binned[pos] = make_int2(((d4.y & 255) << 17) | s4.y, __float_as_int(w4.y));
        pos = atomicAdd(&cur[d4.z >> BSH], 1);
        binned[pos] = make_int2(((d4.z & 255) << 17) | s4.z, __float_as_int(w4.z));
        pos = atomicAdd(&cur[d4.w >> BSH], 1);
        binned[pos] = make_int2(((d4.w & 255) << 17) | s4.w, __float_as_int(w4.w));
    }
}

// ---------------- fused deg + CSR: dinv/row_ptr (pass 1) + rank/copy (pass 2) ------
// Edge record = (src, raw w bits): dinv factors are applied in gemm (src side)
// and in the agg epilogue (dst side, hoisted out of the row sum).
// Both streaming passes 2-deep unrolled for load ILP (binned is L2-hot).
__global__ void k_degcsr(const int2* __restrict__ binned, const int* __restrict__ binStart,
                         float* __restrict__ dinv, int* __restrict__ row_ptr,
                         int2* __restrict__ edges, int n) {
    __shared__ int   cnt[256];
    __shared__ float ws[256];
    __shared__ int   off[256];
    __shared__ int   rp[256];
    int b = blockIdx.x, t = threadIdx.x;
    cnt[t] = 0; ws[t] = 0.0f;
    __syncthreads();
    int e0 = binStart[b], e1 = binStart[b + 1];
    int e = e0 + t;
    for (; e + 256 < e1; e += 512) {
        int2 r0 = binned[e];
        int2 r1 = binned[e + 256];
        int dl0 = (unsigned)r0.x >> 17;
        int dl1 = (unsigned)r1.x >> 17;
        atomicAdd(&cnt[dl0], 1);
        atomicAdd(&ws[dl0], __int_as_float(r0.y));
        atomicAdd(&cnt[dl1], 1);
        atomicAdd(&ws[dl1], __int_as_float(r1.y));
    }
    if (e < e1) {
        int2 r = binned[e];
        int dl = (unsigned)r.x >> 17;
        atomicAdd(&cnt[dl], 1);
        atomicAdd(&ws[dl], __int_as_float(r.y));
    }
    __syncthreads();
    int v = cnt[t];
    off[t] = v;
    __syncthreads();
    for (int o = 1; o < 256; o <<= 1) {
        int add = (t >= o) ? off[t - o] : 0;
        __syncthreads();
        off[t] += add;
        __syncthreads();
    }
    int node = b * 256 + t;
    rp[t] = e0 + off[t] - v;                 // exclusive row base
    if (node < n) {
        dinv[node] = rsqrtf(1.0f + ws[t]);   // self-loop weight 1
        row_ptr[node] = rp[t];
    }
    if (b == NBIN - 1 && t == 0) row_ptr[n] = binStart[NBIN];
    cnt[t] = 0;                              // reuse as rank cursor
    __syncthreads();
    e = e0 + t;
    for (; e + 256 < e1; e += 512) {         // pass 2: bin is L2-hot, pure rank+copy
        int2 r0 = binned[e];
        int2 r1 = binned[e + 256];
        int dl0 = (unsigned)r0.x >> 17;
        int dl1 = (unsigned)r1.x >> 17;
        int k0 = atomicAdd(&cnt[dl0], 1);
        edges[rp[dl0] + k0] = make_int2(r0.x & 0x1FFFF, r0.y);
        int k1 = atomicAdd(&cnt[dl1], 1);
        edges[rp[dl1] + k1] = make_int2(r1.x & 0x1FFFF, r1.y);
    }
    if (e < e1) {
        int2 r = binned[e];
        int dl = (unsigned)r.x >> 17;
        int k = atomicAdd(&cnt[dl], 1);
        edges[rp[dl] + k] = make_int2(r.x & 0x1FFFF, r.y);
    }
}

// ---------------- dense: T' = dinv ⊙ (X @ W) via MFMA 16x16x32 f16 ----------------
// Wave computes 32 rows (2 tiles of 16). A/B frag: lane&15 = row/col,
// 8 contiguous k at (lane>>4)*8. C/D: col=lane&15, row=(lane>>4)*4+reg.
template <int IN_HALF>
__global__ void k_gemm(const void* __restrict__ Xv, const float* __restrict__ W,
                       const float* __restrict__ dinv, __half* __restrict__ T, int n) {
    int wid = (int)((blockIdx.x * blockDim.x + threadIdx.x) >> 6);
    int lane = threadIdx.x & 63;
    int col16 = lane & 15, kg = lane >> 4;
    int r0 = wid * 32;
    if (r0 >= n) return;
    // B fragments: bf[kk][ct], elem j = W[kk*32 + kg*8 + j][ct*16 + col16]
    f16x8 bf[2][4];
#pragma unroll
    for (int kk = 0; kk < 2; kk++)
#pragma unroll
        for (int ct = 0; ct < 4; ct++) {
            f16x8 b;
#pragma unroll
            for (int j = 0; j < 8; j++)
                b[j] = (_Float16)W[(size_t)(kk * 32 + kg * 8 + j) * D + ct * 16 + col16];
            bf[kk][ct] = b;
        }
#pragma unroll
    for (int tt = 0; tt < 2; tt++) {
        int row = r0 + tt * 16 + col16;           // this lane's A row
        f16x8 a0, a1;
        if (IN_HALF) {
            const _Float16* xr = (const _Float16*)Xv + (size_t)row * D;
            a0 = *(const f16x8*)(xr + kg * 8);
            a1 = *(const f16x8*)(xr + 32 + kg * 8);
        } else {
            const float* xr = (const float*)Xv + (size_t)row * D;
#pragma unroll
            for (int j = 0; j < 8; j++) {
                a0[j] = (_Float16)xr[kg * 8 + j];
                a1[j] = (_Float16)xr[32 + kg * 8 + j];
            }
        }
        float dvr[4];
#pragma unroll
        for (int r = 0; r < 4; r++) dvr[r] = dinv[r0 + tt * 16 + kg * 4 + r];
#pragma unroll
        for (int ct = 0; ct < 4; ct++) {
            f32x4 z = {0.0f, 0.0f, 0.0f, 0.0f};
            z = __builtin_amdgcn_mfma_f32_16x16x32_f16(a0, bf[0][ct], z, 0, 0, 0);
            z = __builtin_amdgcn_mfma_f32_16x16x32_f16(a1, bf[1][ct], z, 0, 0, 0);
            __half* to = T + (size_t)(r0 + tt * 16 + kg * 4) * D + ct * 16 + col16;
#pragma unroll
            for (int r = 0; r < 4; r++)
                to[(size_t)r * D] = __float2half(z[r] * dvr[r]);
        }
    }
}

// ---------------- aggregation on pre-scaled fp16 rows (proven 56µs form) ------------
// acc = Σ w_e·T'[s] + T'[v]  (self-loop weight 1); out = relu(dv·acc + b).
// Tiers 16/8/4/2 edges (ILP 8/4/2/1 per half-wave) + odd tail; NT edge loads.
template <int FUSE_W3>
__global__ void k_agg(const __half2* __restrict__ T2, const int* __restrict__ row_ptr,
                      const int2* __restrict__ edges, const float* __restrict__ dinv,
                      const float* __restrict__ bias, const float* __restrict__ W3,
                      void* __restrict__ outv, int n) {
    int wave = (int)((blockIdx.x * blockDim.x + threadIdx.x) >> 6);
    int lane = threadIdx.x & 63;
    if (wave >= n) return;
    int c = lane & 31;
    int h = lane >> 5;
    int beg = row_ptr[wave], end = row_ptr[wave + 1];
    float ax = 0.0f, ay = 0.0f, bx = 0.0f, by = 0.0f;
    int i = beg;
    for (; i + 16 <= end; i += 16) {
        int2 er[8];
#pragma unroll
        for (int j = 0; j < 8; j++) er[j] = ldnt2(&edges[i + 2 * j + h]);
        __half2 tv[8];
#pragma unroll
        for (int j = 0; j < 8; j++) tv[j] = T2[(size_t)er[j].x * 32 + c];
#pragma unroll
        for (int j = 0; j < 8; j++) {
            float nv = __int_as_float(er[j].y);
            float2 f = __half22float2(tv[j]);
            if (j & 1) { bx += nv * f.x; by += nv * f.y; }
            else       { ax += nv * f.x; ay += nv * f.y; }
        }
    }
    if (i + 8 <= end) {
        int2 er[4];
#pragma unroll
        for (int j = 0; j < 4; j++) er[j] = ldnt2(&edges[i + 2 * j + h]);
        __half2 tv[4];
#pragma unroll
        for (int j = 0; j < 4; j++) tv[j] = T2[(size_t)er[j].x * 32 + c];
#pragma unroll
        for (int j = 0; j < 4; j++) {
            float nv = __int_as_float(er[j].y);
            float2 f = __half22float2(tv[j]);
            if (j & 1) { bx += nv * f.x; by += nv * f.y; }
            else       { ax += nv * f.x; ay += nv * f.y; }
        }
        i += 8;
    }
    if (i + 4 <= end) {
        int2 er[2];
#pragma unroll
        for (int j = 0; j < 2; j++) er[j] = ldnt2(&edges[i + 2 * j + h]);
#pragma unroll
        for (int j = 0; j < 2; j++) {
            float nv = __int_as_float(er[j].y);
            float2 f = __half22float2(T2[(size_t)er[j].x * 32 + c]);
            if (j & 1) { bx += nv * f.x; by += nv * f.y; }
            else       { ax += nv * f.x; ay += nv * f.y; }
        }
        i += 4;
    }
    if (i + 2 <= end) {
        int2 e = ldnt2(&edges[i + h]);
        float nv = __int_as_float(e.y);
        float2 f = __half22float2(T2[(size_t)e.x * 32 + c]);
        ax += nv * f.x; ay += nv * f.y;
        i += 2;
    }
    if (i < end && h == 0) {                       // odd leftover: half 0 only
        int2 e = ldnt2(&edges[i]);
        float nv = __int_as_float(e.y);
        float2 f = __half22float2(T2[(size_t)e.x * 32 + c]);
        ax += nv * f.x; ay += nv * f.y;
    }
    ax += bx; ay += by;
    ax += __shfl_xor(ax, 32);                      // combine halves
    ay += __shfl_xor(ay, 32);
    float dv = dinv[wave];
    float2 self = __half22float2(T2[(size_t)wave * 32 + c]);  // pre-scaled by dinv[v]
    float hx = fmaxf(dv * (ax + self.x) + bias[2 * c], 0.0f);
    float hy = fmaxf(dv * (ay + self.y) + bias[2 * c + 1], 0.0f);
    if (FUSE_W3) {
        float pp = hx * W3[2 * c] + hy * W3[2 * c + 1];
#pragma unroll
        for (int off = 16; off; off >>= 1) pp += __shfl_xor(pp, off);
        if (lane == 0) ((float*)outv)[wave] = dv * pp;   // store pre-scaled t3'
    } else {
        if (lane < 32) ((__half2*)outv)[(size_t)wave * 32 + c] = __floats2half2_rn(hx, hy);
    }
}

// ---------------- layer 3 on pre-scaled t3': sigmoid(dv·(Σ w·t3'[s] + t3'[v]) + b3) ----
__global__ void k_agg3(const float* __restrict__ t3, const int* __restrict__ row_ptr,
                       const int2* __restrict__ edges, const float* __restrict__ dinv,
                       const float* __restrict__ b3, float* __restrict__ out, int n) {
    int v = blockIdx.x * blockDim.x + threadIdx.x;
    if (v >= n) return;
    float acc0 = t3[v];                        // self-loop, weight 1
    float acc1 = 0.0f;
    int beg = row_ptr[v], end = row_ptr[v + 1];
    int i = beg;
    for (; i + 8 <= end; i += 8) {
        int2 er[8]; float av[8];
#pragma unroll
        for (int j = 0; j < 8; j++) er[j] = ldnt2(&edges[i + j]);
#pragma unroll
        for (int j = 0; j < 8; j++) av[j] = t3[er[j].x];
#pragma unroll
        for (int j = 0; j < 8; j++) {
            if (j & 1) acc1 += __int_as_float(er[j].y) * av[j];
            else       acc0 += __int_as_float(er[j].y) * av[j];
        }
    }
    for (; i < end; i++) {
        int2 e = ldnt2(&edges[i]);
        acc0 += __int_as_float(e.y) * t3[e.x];
    }
    float z = dinv[v] * (acc0 + acc1) + b3[0];
    out[v] = 1.0f / (1.0f + expf(-z));
}

extern "C" void kernel_launch(void* const* d_in, const int* in_sizes, int n_in,
                              void* d_out, int out_size, void* d_ws, size_t ws_size,
                              hipStream_t stream) {
    const float* x  = (const float*)d_in[0];
    const int*   ei = (const int*)d_in[1];
    const float* w  = (const float*)d_in[2];
    const float* W1 = (const float*)d_in[3];
    const float* b1 = (const float*)d_in[4];
    const float* W2 = (const float*)d_in[5];
    const float* b2 = (const float*)d_in[6];
    const float* W3 = (const float*)d_in[7];
    const float* b3 = (const float*)d_in[8];
    float* out = (float*)d_out;

    const int N = NN, E = NE;
    const int* src = ei;
    const int* dst = ei + E;

    // workspace carve (256B aligned)
    char* p = (char*)d_ws;
    auto alloc = [&](size_t bytes) -> char* {
        char* r = p;
        p += (bytes + 255) & ~(size_t)255;
        return r;
    };
    float* dinv    = (float*)alloc((size_t)N * 4);
    int*   row_ptr = (int*)alloc((size_t)(N + 1) * 4);
    int*   binStart= (int*)alloc((NBIN + 1) * 4);
    int*   binTot  = (int*)alloc(NBIN * 4);
    int*   counts  = (int*)alloc((size_t)NBB * NBIN * 4);
    int2*  binned  = (int2*)alloc((size_t)E * 8);       // bin-ordered records
    int2*  edges   = (int2*)alloc((size_t)E * 8);       // compact CSR (src, raw w)
    __half* bufA   = (__half*)alloc((size_t)N * D * 2);
    __half* bufB   = (__half*)alloc((size_t)N * D * 2);
    float* t3      = (float*)alloc((size_t)N * 4);

    const int BT = 256;
    int gN = (N + BT - 1) / BT;
    int gW = (N * 64 + BT - 1) / BT;               // wave-per-node grids (4 waves/block)
    int nWaves = (N + 31) / 32;                    // gemm: wave per 32 rows
    int gG = (nWaves * 64 + BT - 1) / BT;

    // --- CSR build: zero global atomics, parallel scans ---
    k_binhist<<<NBB, BT, 0, stream>>>(dst, counts, E);
    k_binscan<<<NBIN, BT, 0, stream>>>(counts, binTot);
    k_binscan2<<<1, 512, 0, stream>>>(binTot, binStart);
    k_binscatter<<<NBB, BT, 0, stream>>>(src, dst, w, counts, binStart, binned, E);
    k_degcsr<<<NBIN, BT, 0, stream>>>(binned, binStart, dinv, row_ptr, edges, N);

    // --- layer 1 ---
    k_gemm<0><<<gG, BT, 0, stream>>>(x, W1, dinv, bufA, N);
    k_agg<0><<<gW, BT, 0, stream>>>((const __half2*)bufA, row_ptr, edges, dinv, b1, nullptr, bufB, N);
    // --- layer 2 (fused h2 @ W3 epilogue -> t3') ---
    k_gemm<1><<<gG, BT, 0, stream>>>(bufB, W2, dinv, bufA, N);
    k_agg<1><<<gW, BT, 0, stream>>>((const __half2*)bufA, row_ptr, edges, dinv, b2, W3, t3, N);
    // --- layer 3: scalar aggregation + bias + sigmoid ---
    k_agg3<<<gN, BT, 0, stream>>>(t3, row_ptr, edges, dinv, b3, out, N);
}